// Round 16
// baseline (397.177 us; speedup 1.0000x reference)
//
#include <hip/hip_runtime.h>
#include <hip/hip_bf16.h>

// GCN: N=50000, E=800000, hidden 64, 5 convs (relu on first 4).
// f32 tensors, int32 edge_index, f32 d_out[N].  ws_size in [19.8, 26.0) MB.
// r10-r14: gather layers pinned at 44+-4 us across 3 inner-loop structures,
// occupancy 50->75%, barrier/W changes. Invariant: 12500 short-lived blocks/kernel,
// 1 node per wave (cold setup chain per node, launch/drain churn).
// This round: 8 nodes per wave (grid 1563 for gconv/gconv_z/out; mm_in grid-stride
// 784). Setup (row_start/dinv/W) L1-amortized 8x; discriminates overhead-bound vs
// memory-side-saturation for the 44 us plateau. CSR build unchanged from r15.
// Workspace (~18.2 MB): gA bf16[N*64] | gB bf16[N*64] | bucket u16[E] | staging u32[E]
//   | row_start i32[N+1] | dinv f32[N] | zg f32[N] | bktcnt i32[256] | bktbase i32[257]
//   | bcur i32[256]

#define TPB 256
#define EPT 8                    // edges per thread in k_bin / k_bktcnt
#define CHUNK (TPB * EPT)        // 2048 edges per block
#define NPW 8                    // nodes per wave in gather kernels
typedef __hip_bfloat16 bf16;
#define B2F __bfloat162float

__global__ void k_zero_b(int* __restrict__ bktcnt) {
    bktcnt[threadIdx.x] = 0;
}

// Per-bucket (dst>>8) edge counts via LDS histogram.
__global__ __launch_bounds__(TPB) void k_bktcnt(
    const int* __restrict__ dst, int* __restrict__ bktcnt, int E, int n) {
    __shared__ int h[256];
    int tid = threadIdx.x;
    h[tid] = 0;
    __syncthreads();
    int e0 = blockIdx.x * CHUNK;
#pragma unroll
    for (int u = 0; u < EPT; ++u) {
        int e = e0 + u * TPB + tid;
        if (e < E) {
            int d = dst[e];
            if ((unsigned)d < (unsigned)n) atomicAdd(&h[d >> 8], 1);
        }
    }
    __syncthreads();
    if (h[tid]) atomicAdd(&bktcnt[tid], h[tid]);
}

// Exclusive scan of 256 bucket counts -> bktbase[257]; bcur = bktbase copy.
__global__ void k_bktscan(const int* __restrict__ bktcnt, int* __restrict__ bktbase,
                          int* __restrict__ bcur) {
    __shared__ int s[256];
    int t = threadIdx.x;
    int v = bktcnt[t];
    s[t] = v;
    __syncthreads();
    for (int off = 1; off < 256; off <<= 1) {
        int u = (t >= off) ? s[t - off] : 0;
        __syncthreads();
        s[t] += u;
        __syncthreads();
    }
    int excl = s[t] - v;
    bktbase[t] = excl;
    bcur[t] = excl;
    if (t == 255) bktbase[256] = s[t];
}

// Pass 1: bin edges by dst>>8 into staging (record = src | (dst&255)<<16).
__global__ __launch_bounds__(TPB) void k_bin(
    const int* __restrict__ src, const int* __restrict__ dst,
    int* __restrict__ bcur, unsigned* __restrict__ staging, int E, int n) {
    __shared__ int hcnt[256];
    __shared__ int hbase[256];
    int tid = threadIdx.x;
    int e0 = blockIdx.x * CHUNK;
    hcnt[tid] = 0;
    __syncthreads();

    int eb[EPT];
    unsigned rec[EPT];
#pragma unroll
    for (int u = 0; u < EPT; ++u) {
        int e = e0 + u * TPB + tid;
        eb[u] = -1;
        if (e < E) {
            int d = dst[e], s = src[e];
            if ((unsigned)d < (unsigned)n && (unsigned)s < (unsigned)n) {
                eb[u] = d >> 8;
                rec[u] = (unsigned)s | ((unsigned)(d & 255) << 16);
                atomicAdd(&hcnt[eb[u]], 1);
            }
        }
    }
    __syncthreads();
    int c = hcnt[tid];
    hbase[tid] = (c > 0) ? atomicAdd(&bcur[tid], c) : 0;
    hcnt[tid] = 0;
    __syncthreads();
#pragma unroll
    for (int u = 0; u < EPT; ++u) {
        if (eb[u] >= 0) {
            int r = atomicAdd(&hcnt[eb[u]], 1);
            int pos = hbase[eb[u]] + r;
            if ((unsigned)pos < (unsigned)E) staging[pos] = rec[u];  // replay-safe
        }
    }
}

// Pass 2: one block per bucket. Per-node histogram + prefix in LDS -> row_start,
// dinv, and record placement via LDS cursors (no global per-node atomics).
__global__ __launch_bounds__(TPB) void k_unbin2(
    const unsigned* __restrict__ staging, const int* __restrict__ bktbase,
    int* __restrict__ row_start, float* __restrict__ dinv,
    unsigned short* __restrict__ bucket, int E, int n) {
    __shared__ int cnt[256];
    __shared__ int scn[256];
    __shared__ int cur[256];
    int b = blockIdx.x, tid = threadIdx.x;
    int lo = bktbase[b], hi = bktbase[b + 1];
    lo = max(0, min(lo, E)); hi = max(lo, min(hi, E));

    cnt[tid] = 0;
    __syncthreads();
    for (int i = lo + tid; i < hi; i += TPB)
        atomicAdd(&cnt[(staging[i] >> 16) & 255], 1);
    __syncthreads();

    int v = cnt[tid];
    scn[tid] = v;
    __syncthreads();
    for (int off = 1; off < 256; off <<= 1) {
        int u = (tid >= off) ? scn[tid - off] : 0;
        __syncthreads();
        scn[tid] += u;
        __syncthreads();
    }
    int excl = scn[tid] - v;
    int base = min(lo + excl, E);
    cur[tid] = base;
    int d = (b << 8) + tid;
    if (d < n) {
        row_start[d] = base;
        dinv[d] = rsqrtf((float)v + 1.0f);     // +1 self-loop
        if (d == n - 1) row_start[n] = min(base + v, E);
    }
    __syncthreads();

    for (int i = lo + tid; i < hi; i += TPB) {
        unsigned r = staging[i];
        int t = (r >> 16) & 255;
        int pos = atomicAdd(&cur[t], 1);
        if ((unsigned)pos < (unsigned)E) bucket[pos] = (unsigned short)(r & 0xffffu);
    }
}

// g1[i][j] = (sum_{k<4} x[i][k] * W_in[k][j]) * dinv[i]   (premultiplied, grid-stride)
__global__ void k_mm_in(const float* __restrict__ x, const float* __restrict__ W,
                        const float* __restrict__ dinv, bf16* __restrict__ g, int n) {
    int stride = gridDim.x * blockDim.x;
    for (int t = blockIdx.x * blockDim.x + threadIdx.x; t < n * 64; t += stride) {
        int i = t >> 6, j = t & 63;
        float acc = 0.f;
#pragma unroll
        for (int k = 0; k < 4; ++k) acc = fmaf(x[i * 4 + k], W[k * 64 + j], acc);
        g[t] = __float2bfloat16(acc * dinv[i]);
    }
}

__device__ __forceinline__ void acc_quad(float4& a, uint2 w) {
    a.x += __uint_as_float(w.x << 16);
    a.y += __uint_as_float(w.x & 0xffff0000u);
    a.z += __uint_as_float(w.y << 16);
    a.w += __uint_as_float(w.y & 0xffff0000u);
}

// Quad gather: 4 edges per load instruction; lane group g=lane>>4 takes edge k+g,
// lane i=lane&15 loads uint2 = 4 packed bf16 feats. Each group writes its float4
// partial to its own LDS row; the (same-wave) transform sums the 4 rows.
__device__ __forceinline__ void agg_row_quad(const bf16* __restrict__ g,
                                             const unsigned short* __restrict__ bucket,
                                             int k0, int k1, int d, float* __restrict__ sVp,
                                             int lane, unsigned nm1, unsigned Em1) {
    int grp = lane >> 4, i = lane & 15;
    float4 a = {0.f, 0.f, 0.f, 0.f};
    if (grp == 0) {  // self term
        uint2 w = *(const uint2*)(g + (size_t)d * 64 + 4 * i);
        acc_quad(a, w);
    }
    for (int base = k0; base < k1; base += 64) {
        int cnt = min(64, k1 - base);
        int rec = bucket[min((unsigned)(base + lane), Em1)];  // coalesced u16 load
        int k = 0;
        for (; k + 16 <= cnt; k += 16) {                      // 16 edges, 4 quad loads
            unsigned s0 = min((unsigned)__shfl(rec, k + 0 + grp), nm1);
            unsigned s1 = min((unsigned)__shfl(rec, k + 4 + grp), nm1);
            unsigned s2 = min((unsigned)__shfl(rec, k + 8 + grp), nm1);
            unsigned s3 = min((unsigned)__shfl(rec, k + 12 + grp), nm1);
            uint2 w0 = *(const uint2*)(g + (size_t)s0 * 64 + 4 * i);
            uint2 w1 = *(const uint2*)(g + (size_t)s1 * 64 + 4 * i);
            uint2 w2 = *(const uint2*)(g + (size_t)s2 * 64 + 4 * i);
            uint2 w3 = *(const uint2*)(g + (size_t)s3 * 64 + 4 * i);
            acc_quad(a, w0); acc_quad(a, w1); acc_quad(a, w2); acc_quad(a, w3);
        }
        for (; k < cnt; k += 4) {                             // tail, predicated
            int e = k + grp;
            unsigned s = min((unsigned)__shfl(rec, min(e, 63)), nm1);
            uint2 w = *(const uint2*)(g + (size_t)s * 64 + 4 * i);
            if (e < cnt) acc_quad(a, w);
        }
    }
    ((float4*)(sVp + grp * 64))[i] = a;   // partial row per group (wave-local)
}

// Fused layer: one wave per 8 nodes (32 nodes/block, grid 1563). Per node:
// gather -> wave-local LDS partials -> relu(dd*sum+bias) -> (a@W)*dd.
// W from global (L1-hot after node 0); row_start/dinv L1-hot; no barriers.
__global__ __launch_bounds__(TPB) void k_gconv(
    const bf16* __restrict__ gIn, const float* __restrict__ dinv,
    const int* __restrict__ row_start, const unsigned short* __restrict__ bucket,
    const float* __restrict__ bias, const float* __restrict__ W,
    bf16* __restrict__ gOut, int n, int E) {
    __shared__ float sVp[4][4 * 64];     // [wave][group][64]
    int tid = threadIdx.x;
    int r = tid >> 6, j = tid & 63;
    int d0 = (blockIdx.x * 4 + r) * NPW;
    if (d0 >= n) return;                  // wave-uniform
    unsigned nm1 = (unsigned)(n - 1), Em1 = (unsigned)(E - 1);
    float bj = bias[j];
    for (int it = 0; it < NPW; ++it) {
        int d = d0 + it;
        if (d >= n) break;                // wave-uniform
        float dd = dinv[d];
        int k0 = row_start[d], k1 = row_start[d + 1];
        k1 = min(k1, E); k0 = max(min(k0, k1), 0);
        agg_row_quad(gIn, bucket, k0, k1, d, sVp[r], j, nm1, Em1);
        // wave-local LDS ordering (lgkmcnt) — no barrier
        float v = sVp[r][j] + sVp[r][64 + j] + sVp[r][128 + j] + sVp[r][192 + j];
        float a = fmaxf(fmaf(dd, v, bj), 0.f);
        sVp[r][j] = a;                    // row 0 holds the activation (wave-local)
        const float4* ap = (const float4*)&sVp[r][0];
        float acc0 = 0.f, acc1 = 0.f, acc2 = 0.f, acc3 = 0.f;
#pragma unroll
        for (int k4 = 0; k4 < 16; ++k4) {
            float4 a4 = ap[k4];           // wave-uniform address -> broadcast b128
            acc0 = fmaf(a4.x, W[(4 * k4 + 0) * 64 + j], acc0);
            acc1 = fmaf(a4.y, W[(4 * k4 + 1) * 64 + j], acc1);
            acc2 = fmaf(a4.z, W[(4 * k4 + 2) * 64 + j], acc2);
            acc3 = fmaf(a4.w, W[(4 * k4 + 3) * 64 + j], acc3);
        }
        float acc = (acc0 + acc1) + (acc2 + acc3);
        gOut[(size_t)d * 64 + j] = __float2bfloat16(acc * dd);
    }
}

// Last hidden conv fused with 64->1 matmul, 8 nodes per wave.
__global__ __launch_bounds__(TPB) void k_gconv_z(
    const bf16* __restrict__ gIn, const float* __restrict__ dinv,
    const int* __restrict__ row_start, const unsigned short* __restrict__ bucket,
    const float* __restrict__ bias, const float* __restrict__ Wout,
    float* __restrict__ zg, int n, int E) {
    __shared__ float sVp[4][4 * 64];
    int tid = threadIdx.x;
    int r = tid >> 6, j = tid & 63;
    int d0 = (blockIdx.x * 4 + r) * NPW;
    if (d0 >= n) return;                  // wave-uniform
    unsigned nm1 = (unsigned)(n - 1), Em1 = (unsigned)(E - 1);
    float bj = bias[j], wj = Wout[j];
    for (int it = 0; it < NPW; ++it) {
        int d = d0 + it;
        if (d >= n) break;
        float dd = dinv[d];
        int k0 = row_start[d], k1 = row_start[d + 1];
        k1 = min(k1, E); k0 = max(min(k0, k1), 0);
        agg_row_quad(gIn, bucket, k0, k1, d, sVp[r], j, nm1, Em1);
        float v = sVp[r][j] + sVp[r][64 + j] + sVp[r][128 + j] + sVp[r][192 + j];
        float a = fmaxf(fmaf(dd, v, bj), 0.f) * wj;
#pragma unroll
        for (int off = 32; off > 0; off >>= 1) a += __shfl_down(a, off);
        if (j == 0) zg[d] = a * dd;
    }
}

// out[d] = dd*(zg[d] + sum zg[s]) + b_out.  8 nodes per wave, lane = neighbor.
__global__ __launch_bounds__(TPB) void k_out(
    const float* __restrict__ zg, const float* __restrict__ dinv,
    const int* __restrict__ row_start, const unsigned short* __restrict__ bucket,
    const float* __restrict__ b_out, float* __restrict__ out, int n, int E) {
    int tid = threadIdx.x;
    int r = tid >> 6, lane = tid & 63;
    int d0 = (blockIdx.x * 4 + r) * NPW;
    if (d0 >= n) return;                  // wave-uniform
    unsigned nm1 = (unsigned)(n - 1);
    float bo = b_out[0];
    for (int it = 0; it < NPW; ++it) {
        int d = d0 + it;
        if (d >= n) break;
        int k0 = row_start[d], k1 = row_start[d + 1];
        k1 = min(k1, E); k0 = max(min(k0, k1), 0);
        float v = 0.f;
        for (int k = k0 + lane; k < k1; k += 64) {
            unsigned s = min((unsigned)bucket[k], nm1);
            v += zg[s];
        }
#pragma unroll
        for (int off = 32; off > 0; off >>= 1) v += __shfl_down(v, off);
        if (lane == 0) out[d] = fmaf(zg[d] + v, dinv[d], bo);
    }
}

extern "C" void kernel_launch(void* const* d_in, const int* in_sizes, int n_in,
                              void* d_out, int out_size, void* d_ws, size_t ws_size,
                              hipStream_t stream) {
    const float* x     = (const float*)d_in[0];
    const int*   ei    = (const int*)d_in[1];
    const float* W_in  = (const float*)d_in[2];
    const float* b_in  = (const float*)d_in[3];
    const float* W_h   = (const float*)d_in[4];
    const float* b_h   = (const float*)d_in[5];
    const float* W_out = (const float*)d_in[6];
    const float* b_out = (const float*)d_in[7];
    float* out = (float*)d_out;

    int N = in_sizes[0] / 4;
    int E = in_sizes[1] / 2;
    const int* src = ei;
    const int* dst = ei + E;

    char* ws = (char*)d_ws;
    bf16* gA               = (bf16*)ws;           ws += (size_t)N * 64 * 2;
    bf16* gB               = (bf16*)ws;           ws += (size_t)N * 64 * 2;
    unsigned short* bucket = (unsigned short*)ws; ws += (size_t)E * 2;
    unsigned* staging      = (unsigned*)ws;       ws += (size_t)E * 4;
    int*  row_start        = (int*)ws;            ws += (size_t)(N + 1) * 4;
    float* dinv            = (float*)ws;          ws += (size_t)N * 4;
    float* zg              = (float*)ws;          ws += (size_t)N * 4;
    int*  bktcnt           = (int*)ws;            ws += 256 * 4;
    int*  bktbase          = (int*)ws;            ws += 257 * 4;
    int*  bcur             = (int*)ws;            // 256 ints

    int B   = (N + 255) >> 8;             // dst buckets (196 for N=50000; <=256)
    int gBin = (E + CHUNK - 1) / CHUNK;   // 391
    int gG  = (N + 4 * NPW - 1) / (4 * NPW);  // 1563 (8 nodes/wave, 4 waves/block)
    int gMM = 784;                        // grid-stride matmul

    // ---- CSR build + norms (bucket-centric) ----
    k_zero_b<<<1, 256, 0, stream>>>(bktcnt);
    k_bktcnt<<<gBin, TPB, 0, stream>>>(dst, bktcnt, E, N);
    k_bktscan<<<1, 256, 0, stream>>>(bktcnt, bktbase, bcur);
    k_bin<<<gBin, TPB, 0, stream>>>(src, dst, bcur, staging, E, N);
    k_unbin2<<<B, TPB, 0, stream>>>(staging, bktbase, row_start, dinv, bucket, E, N);

    // ---- layers (feature buffers premultiplied by dinv) ----
    k_mm_in<<<gMM, TPB, 0, stream>>>(x, W_in, dinv, gA, N);
    k_gconv<<<gG, TPB, 0, stream>>>(gA, dinv, row_start, bucket, b_in, W_h, gB, N, E);
    k_gconv<<<gG, TPB, 0, stream>>>(gB, dinv, row_start, bucket, b_h, W_h + 4096, gA, N, E);
    k_gconv<<<gG, TPB, 0, stream>>>(gA, dinv, row_start, bucket, b_h + 64, W_h + 8192, gB, N, E);
    k_gconv_z<<<gG, TPB, 0, stream>>>(gB, dinv, row_start, bucket, b_h + 128, W_out, zg, N, E);
    k_out<<<gG, TPB, 0, stream>>>(zg, dinv, row_start, bucket, b_out, out, N, E);
}

// Round 17
// 261.295 us; speedup vs baseline: 1.5200x; 1.5200x over previous
//
#include <hip/hip_runtime.h>
#include <hip/hip_bf16.h>

// GCN: N=50000, E=800000, hidden 64, 5 convs (relu on first 4).
// f32 tensors, int32 edge_index, f32 d_out[N].  ws_size in [19.8, 26.0) MB.
// r16 post-mortem: 8 nodes/wave regressed (VGPR 96, occ 16%) -> plateau is NOT
// launch churn. Reverted to r15 (273 us). This round's single change: OCT gather —
// 8 edges per load instruction (8-lane groups, uint4=16B/lane, one instr = 8 full
// 128B rows). Halves gather VMEM instructions at identical line count: the clean
// instruction-side vs line-service discriminator. All else identical to r15.
// Workspace (~18.2 MB): gA bf16[N*64] | gB bf16[N*64] | bucket u16[E] | staging u32[E]
//   | row_start i32[N+1] | dinv f32[N] | zg f32[N] | bktcnt i32[256] | bktbase i32[257]
//   | bcur i32[256]

#define TPB 256
#define EPT 8                    // edges per thread in k_bin / k_bktcnt
#define CHUNK (TPB * EPT)        // 2048 edges per block
typedef __hip_bfloat16 bf16;
#define B2F __bfloat162float

__global__ void k_zero_b(int* __restrict__ bktcnt) {
    bktcnt[threadIdx.x] = 0;
}

// Per-bucket (dst>>8) edge counts via LDS histogram.
__global__ __launch_bounds__(TPB) void k_bktcnt(
    const int* __restrict__ dst, int* __restrict__ bktcnt, int E, int n) {
    __shared__ int h[256];
    int tid = threadIdx.x;
    h[tid] = 0;
    __syncthreads();
    int e0 = blockIdx.x * CHUNK;
#pragma unroll
    for (int u = 0; u < EPT; ++u) {
        int e = e0 + u * TPB + tid;
        if (e < E) {
            int d = dst[e];
            if ((unsigned)d < (unsigned)n) atomicAdd(&h[d >> 8], 1);
        }
    }
    __syncthreads();
    if (h[tid]) atomicAdd(&bktcnt[tid], h[tid]);
}

// Exclusive scan of 256 bucket counts -> bktbase[257]; bcur = bktbase copy.
__global__ void k_bktscan(const int* __restrict__ bktcnt, int* __restrict__ bktbase,
                          int* __restrict__ bcur) {
    __shared__ int s[256];
    int t = threadIdx.x;
    int v = bktcnt[t];
    s[t] = v;
    __syncthreads();
    for (int off = 1; off < 256; off <<= 1) {
        int u = (t >= off) ? s[t - off] : 0;
        __syncthreads();
        s[t] += u;
        __syncthreads();
    }
    int excl = s[t] - v;
    bktbase[t] = excl;
    bcur[t] = excl;
    if (t == 255) bktbase[256] = s[t];
}

// Pass 1: bin edges by dst>>8 into staging (record = src | (dst&255)<<16).
__global__ __launch_bounds__(TPB) void k_bin(
    const int* __restrict__ src, const int* __restrict__ dst,
    int* __restrict__ bcur, unsigned* __restrict__ staging, int E, int n) {
    __shared__ int hcnt[256];
    __shared__ int hbase[256];
    int tid = threadIdx.x;
    int e0 = blockIdx.x * CHUNK;
    hcnt[tid] = 0;
    __syncthreads();

    int eb[EPT];
    unsigned rec[EPT];
#pragma unroll
    for (int u = 0; u < EPT; ++u) {
        int e = e0 + u * TPB + tid;
        eb[u] = -1;
        if (e < E) {
            int d = dst[e], s = src[e];
            if ((unsigned)d < (unsigned)n && (unsigned)s < (unsigned)n) {
                eb[u] = d >> 8;
                rec[u] = (unsigned)s | ((unsigned)(d & 255) << 16);
                atomicAdd(&hcnt[eb[u]], 1);
            }
        }
    }
    __syncthreads();
    int c = hcnt[tid];
    hbase[tid] = (c > 0) ? atomicAdd(&bcur[tid], c) : 0;
    hcnt[tid] = 0;
    __syncthreads();
#pragma unroll
    for (int u = 0; u < EPT; ++u) {
        if (eb[u] >= 0) {
            int r = atomicAdd(&hcnt[eb[u]], 1);
            int pos = hbase[eb[u]] + r;
            if ((unsigned)pos < (unsigned)E) staging[pos] = rec[u];  // replay-safe
        }
    }
}

// Pass 2: one block per bucket. Per-node histogram + prefix in LDS -> row_start,
// dinv, and record placement via LDS cursors (no global per-node atomics).
__global__ __launch_bounds__(TPB) void k_unbin2(
    const unsigned* __restrict__ staging, const int* __restrict__ bktbase,
    int* __restrict__ row_start, float* __restrict__ dinv,
    unsigned short* __restrict__ bucket, int E, int n) {
    __shared__ int cnt[256];
    __shared__ int scn[256];
    __shared__ int cur[256];
    int b = blockIdx.x, tid = threadIdx.x;
    int lo = bktbase[b], hi = bktbase[b + 1];
    lo = max(0, min(lo, E)); hi = max(lo, min(hi, E));

    cnt[tid] = 0;
    __syncthreads();
    for (int i = lo + tid; i < hi; i += TPB)
        atomicAdd(&cnt[(staging[i] >> 16) & 255], 1);
    __syncthreads();

    int v = cnt[tid];
    scn[tid] = v;
    __syncthreads();
    for (int off = 1; off < 256; off <<= 1) {
        int u = (tid >= off) ? scn[tid - off] : 0;
        __syncthreads();
        scn[tid] += u;
        __syncthreads();
    }
    int excl = scn[tid] - v;
    int base = min(lo + excl, E);
    cur[tid] = base;
    int d = (b << 8) + tid;
    if (d < n) {
        row_start[d] = base;
        dinv[d] = rsqrtf((float)v + 1.0f);     // +1 self-loop
        if (d == n - 1) row_start[n] = min(base + v, E);
    }
    __syncthreads();

    for (int i = lo + tid; i < hi; i += TPB) {
        unsigned r = staging[i];
        int t = (r >> 16) & 255;
        int pos = atomicAdd(&cur[t], 1);
        if ((unsigned)pos < (unsigned)E) bucket[pos] = (unsigned short)(r & 0xffffu);
    }
}

// g1[i][j] = (sum_{k<4} x[i][k] * W_in[k][j]) * dinv[i]   (premultiplied)
__global__ void k_mm_in(const float* __restrict__ x, const float* __restrict__ W,
                        const float* __restrict__ dinv, bf16* __restrict__ g, int n) {
    int t = blockIdx.x * blockDim.x + threadIdx.x;
    if (t >= n * 64) return;
    int i = t >> 6, j = t & 63;
    float acc = 0.f;
#pragma unroll
    for (int k = 0; k < 4; ++k) acc = fmaf(x[i * 4 + k], W[k * 64 + j], acc);
    g[t] = __float2bfloat16(acc * dinv[i]);
}

__device__ __forceinline__ void acc_oct(float* a, uint4 w) {
    a[0] += __uint_as_float(w.x << 16);
    a[1] += __uint_as_float(w.x & 0xffff0000u);
    a[2] += __uint_as_float(w.y << 16);
    a[3] += __uint_as_float(w.y & 0xffff0000u);
    a[4] += __uint_as_float(w.z << 16);
    a[5] += __uint_as_float(w.z & 0xffff0000u);
    a[6] += __uint_as_float(w.w << 16);
    a[7] += __uint_as_float(w.w & 0xffff0000u);
}

// OCT gather: 8 edges per load instruction. Lane group grp=lane>>3 takes edge
// k+grp; lane i=lane&7 loads uint4 = 8 packed bf16 feats (8 lanes x 16B = full
// 128B row). Each group writes its 8-float partial to its own LDS row; the
// same-wave transform sums the 8 rows.
__device__ __forceinline__ void agg_row_oct(const bf16* __restrict__ g,
                                            const unsigned short* __restrict__ bucket,
                                            int k0, int k1, int d, float* __restrict__ sVp,
                                            int lane, unsigned nm1, unsigned Em1) {
    int grp = lane >> 3, i = lane & 7;
    float a[8] = {0.f, 0.f, 0.f, 0.f, 0.f, 0.f, 0.f, 0.f};
    if (grp == 0) {  // self term
        uint4 w = *(const uint4*)(g + (size_t)d * 64 + 8 * i);
        acc_oct(a, w);
    }
    for (int base = k0; base < k1; base += 64) {
        int cnt = min(64, k1 - base);
        int rec = bucket[min((unsigned)(base + lane), Em1)];  // coalesced u16 load
        int k = 0;
        for (; k + 16 <= cnt; k += 16) {                      // 16 edges, 2 oct loads
            unsigned s0 = min((unsigned)__shfl(rec, k + grp), nm1);
            unsigned s1 = min((unsigned)__shfl(rec, k + 8 + grp), nm1);
            uint4 w0 = *(const uint4*)(g + (size_t)s0 * 64 + 8 * i);
            uint4 w1 = *(const uint4*)(g + (size_t)s1 * 64 + 8 * i);
            acc_oct(a, w0);
            acc_oct(a, w1);
        }
        for (; k < cnt; k += 8) {                             // tail, predicated
            int e = k + grp;
            unsigned s = min((unsigned)__shfl(rec, min(e, 63)), nm1);
            uint4 w = *(const uint4*)(g + (size_t)s * 64 + 8 * i);
            if (e < cnt) acc_oct(a, w);
        }
    }
    float4* row = (float4*)(sVp + grp * 64);
    row[2 * i + 0] = make_float4(a[0], a[1], a[2], a[3]);
    row[2 * i + 1] = make_float4(a[4], a[5], a[6], a[7]);
}

// Fused layer: one wave per node (4 nodes/block). No LDS W tile, no barriers:
// W read from global (L1-resident); sVp wave-local (8 partial rows per wave).
__global__ __launch_bounds__(TPB) void k_gconv(
    const bf16* __restrict__ gIn, const float* __restrict__ dinv,
    const int* __restrict__ row_start, const unsigned short* __restrict__ bucket,
    const float* __restrict__ bias, const float* __restrict__ W,
    bf16* __restrict__ gOut, int n, int E) {
    __shared__ float sVp[4][8 * 64];     // [wave][group][64]
    int tid = threadIdx.x;
    int r = tid >> 6, j = tid & 63;
    int d = blockIdx.x * 4 + r;
    if (d >= n) return;                   // wave-uniform
    float dd = dinv[d];
    int k0 = row_start[d], k1 = row_start[d + 1];
    k1 = min(k1, E); k0 = max(min(k0, k1), 0);
    agg_row_oct(gIn, bucket, k0, k1, d, sVp[r], j, (unsigned)(n - 1), (unsigned)(E - 1));
    // wave-local LDS ordering (lgkmcnt) — no barrier needed
    float v = 0.f;
#pragma unroll
    for (int gq = 0; gq < 8; ++gq) v += sVp[r][gq * 64 + j];
    float a = fmaxf(fmaf(dd, v, bias[j]), 0.f);
    sVp[r][j] = a;                        // row 0 holds the activation (wave-local)
    const float4* ap = (const float4*)&sVp[r][0];
    float acc0 = 0.f, acc1 = 0.f, acc2 = 0.f, acc3 = 0.f;
#pragma unroll
    for (int k4 = 0; k4 < 16; ++k4) {
        float4 a4 = ap[k4];               // wave-uniform address -> broadcast b128
        acc0 = fmaf(a4.x, W[(4 * k4 + 0) * 64 + j], acc0);
        acc1 = fmaf(a4.y, W[(4 * k4 + 1) * 64 + j], acc1);
        acc2 = fmaf(a4.z, W[(4 * k4 + 2) * 64 + j], acc2);
        acc3 = fmaf(a4.w, W[(4 * k4 + 3) * 64 + j], acc3);
    }
    float acc = (acc0 + acc1) + (acc2 + acc3);
    gOut[(size_t)d * 64 + j] = __float2bfloat16(acc * dd);
}

// Last hidden conv fused with 64->1 matmul: zg[d] = (relu(dd*sum+b) . Wout) * dd.
__global__ __launch_bounds__(TPB) void k_gconv_z(
    const bf16* __restrict__ gIn, const float* __restrict__ dinv,
    const int* __restrict__ row_start, const unsigned short* __restrict__ bucket,
    const float* __restrict__ bias, const float* __restrict__ Wout,
    float* __restrict__ zg, int n, int E) {
    __shared__ float sVp[4][8 * 64];
    int tid = threadIdx.x;
    int r = tid >> 6, j = tid & 63;
    int d = blockIdx.x * 4 + r;
    if (d >= n) return;                   // wave-uniform
    float dd = dinv[d];
    int k0 = row_start[d], k1 = row_start[d + 1];
    k1 = min(k1, E); k0 = max(min(k0, k1), 0);
    agg_row_oct(gIn, bucket, k0, k1, d, sVp[r], j, (unsigned)(n - 1), (unsigned)(E - 1));
    float v = 0.f;
#pragma unroll
    for (int gq = 0; gq < 8; ++gq) v += sVp[r][gq * 64 + j];
    float a = fmaxf(fmaf(dd, v, bias[j]), 0.f) * Wout[j];
#pragma unroll
    for (int off = 32; off > 0; off >>= 1) a += __shfl_down(a, off);
    if (j == 0) zg[d] = a * dd;
}

// out[d] = dd*(zg[d] + sum zg[s]) + b_out.  One wave per node, lane = neighbor.
__global__ __launch_bounds__(TPB) void k_out(
    const float* __restrict__ zg, const float* __restrict__ dinv,
    const int* __restrict__ row_start, const unsigned short* __restrict__ bucket,
    const float* __restrict__ b_out, float* __restrict__ out, int n, int E) {
    int t = blockIdx.x * blockDim.x + threadIdx.x;
    int d = t >> 6, lane = t & 63;
    if (d >= n) return;
    int k0 = row_start[d], k1 = row_start[d + 1];
    k1 = min(k1, E); k0 = max(min(k0, k1), 0);
    unsigned nm1 = (unsigned)(n - 1);
    float v = 0.f;
    for (int k = k0 + lane; k < k1; k += 64) {
        unsigned s = min((unsigned)bucket[k], nm1);
        v += zg[s];
    }
#pragma unroll
    for (int off = 32; off > 0; off >>= 1) v += __shfl_down(v, off);
    if (lane == 0) out[d] = fmaf(zg[d] + v, dinv[d], b_out[0]);
}

extern "C" void kernel_launch(void* const* d_in, const int* in_sizes, int n_in,
                              void* d_out, int out_size, void* d_ws, size_t ws_size,
                              hipStream_t stream) {
    const float* x     = (const float*)d_in[0];
    const int*   ei    = (const int*)d_in[1];
    const float* W_in  = (const float*)d_in[2];
    const float* b_in  = (const float*)d_in[3];
    const float* W_h   = (const float*)d_in[4];
    const float* b_h   = (const float*)d_in[5];
    const float* W_out = (const float*)d_in[6];
    const float* b_out = (const float*)d_in[7];
    float* out = (float*)d_out;

    int N = in_sizes[0] / 4;
    int E = in_sizes[1] / 2;
    const int* src = ei;
    const int* dst = ei + E;

    char* ws = (char*)d_ws;
    bf16* gA               = (bf16*)ws;           ws += (size_t)N * 64 * 2;
    bf16* gB               = (bf16*)ws;           ws += (size_t)N * 64 * 2;
    unsigned short* bucket = (unsigned short*)ws; ws += (size_t)E * 2;
    unsigned* staging      = (unsigned*)ws;       ws += (size_t)E * 4;
    int*  row_start        = (int*)ws;            ws += (size_t)(N + 1) * 4;
    float* dinv            = (float*)ws;          ws += (size_t)N * 4;
    float* zg              = (float*)ws;          ws += (size_t)N * 4;
    int*  bktcnt           = (int*)ws;            ws += 256 * 4;
    int*  bktbase          = (int*)ws;            ws += 257 * 4;
    int*  bcur             = (int*)ws;            // 256 ints

    int B   = (N + 255) >> 8;            // dst buckets (196 for N=50000; <=256)
    int gNF = (N * 64 + TPB - 1) / TPB;
    int gN4 = (N + 3) / 4;               // 4 nodes/block (1 wave per node)
    int gBin = (E + CHUNK - 1) / CHUNK;  // 391

    // ---- CSR build + norms (bucket-centric) ----
    k_zero_b<<<1, 256, 0, stream>>>(bktcnt);
    k_bktcnt<<<gBin, TPB, 0, stream>>>(dst, bktcnt, E, N);
    k_bktscan<<<1, 256, 0, stream>>>(bktcnt, bktbase, bcur);
    k_bin<<<gBin, TPB, 0, stream>>>(src, dst, bcur, staging, E, N);
    k_unbin2<<<B, TPB, 0, stream>>>(staging, bktbase, row_start, dinv, bucket, E, N);

    // ---- layers (feature buffers premultiplied by dinv) ----
    k_mm_in<<<gNF, TPB, 0, stream>>>(x, W_in, dinv, gA, N);
    k_gconv<<<gN4, TPB, 0, stream>>>(gA, dinv, row_start, bucket, b_in, W_h, gB, N, E);
    k_gconv<<<gN4, TPB, 0, stream>>>(gB, dinv, row_start, bucket, b_h, W_h + 4096, gA, N, E);
    k_gconv<<<gN4, TPB, 0, stream>>>(gA, dinv, row_start, bucket, b_h + 64, W_h + 8192, gB, N, E);
    k_gconv_z<<<gN4, TPB, 0, stream>>>(gB, dinv, row_start, bucket, b_h + 128, W_out, zg, N, E);
    k_out<<<gN4, TPB, 0, stream>>>(zg, dinv, row_start, bucket, b_out, out, N, E);
}